// Round 1
// baseline (146.042 us; speedup 1.0000x reference)
//
#include <hip/hip_runtime.h>
#include <math.h>

#define SZ 256
#define NKP 68
#define NB 16
#define SK_ITERS 50

// constants
#define INVV 0.03125f                 // 1/(2*sigma^2), sigma=4
#define LOG_A (-4.219507705176107f)   // -log(68)
#define INV_EPS 100.0f                // 1/0.01
#define NEG_EPS (-0.01f)

// workspace float offsets
#define WS_SP   0    // [16] pred heatmap sums
#define WS_ST   16   // [16] target heatmap sums
#define WS_BCE  32   // [1] bce term sum (un-negated, un-normalized)
#define WS_COST 33   // [16] sinkhorn per-batch cost

// ---------------------------------------------------------------------------
// Kernel 1: per-batch heatmap sums via separable identity
//   S_b = sum_n (sum_y gy[b,n,y]) * (sum_x gx[b,n,x])
// grid (68, 16), block 256
// ---------------------------------------------------------------------------
__global__ __launch_bounds__(256) void k_sums(const float* __restrict__ pred,
                                              const float* __restrict__ targ,
                                              float* __restrict__ ws) {
  const int n = blockIdx.x, b = blockIdx.y;
  const float fx = (float)threadIdx.x;

  const float pxp = pred[(b * NKP + n) * 2 + 0] * 255.0f;
  const float pyp = pred[(b * NKP + n) * 2 + 1] * 255.0f;
  const float pxt = targ[(b * NKP + n) * 2 + 0] * 255.0f;
  const float pyt = targ[(b * NKP + n) * 2 + 1] * 255.0f;

  float dxp = fx - pxp, dyp = fx - pyp, dxt = fx - pxt, dyt = fx - pyt;
  float sxp = expf(-dxp * dxp * INVV);
  float syp = expf(-dyp * dyp * INVV);
  float sxt = expf(-dxt * dxt * INVV);
  float syt = expf(-dyt * dyt * INVV);

  for (int o = 32; o; o >>= 1) {
    sxp += __shfl_down(sxp, o);
    syp += __shfl_down(syp, o);
    sxt += __shfl_down(sxt, o);
    syt += __shfl_down(syt, o);
  }
  __shared__ float ls[4][4];
  const int w = threadIdx.x >> 6, lane = threadIdx.x & 63;
  if (lane == 0) { ls[w][0] = sxp; ls[w][1] = syp; ls[w][2] = sxt; ls[w][3] = syt; }
  __syncthreads();
  if (threadIdx.x == 0) {
    float a0 = 0, a1 = 0, a2 = 0, a3 = 0;
    for (int i = 0; i < 4; i++) { a0 += ls[i][0]; a1 += ls[i][1]; a2 += ls[i][2]; a3 += ls[i][3]; }
    atomicAdd(&ws[WS_SP + b], a0 * a1);
    atomicAdd(&ws[WS_ST + b], a2 * a3);
  }
}

// ---------------------------------------------------------------------------
// Sinkhorn: one block per batch, 4 lanes per row (68 rows -> 272 active lanes)
// z_j = (g_j - C_ij)/eps + log_a = 100*g_j + A[k],  A[k] = log_a - 100*C
// ---------------------------------------------------------------------------
__device__ void sink_part(const float* __restrict__ pred,
                          const float* __restrict__ targ,
                          float* __restrict__ ws, int b) {
  __shared__ float fsh[NKP], gsh[NKP], wred[5];
  const int tid = threadIdx.x;
  const int r = tid >> 2, q = tid & 3;
  const bool act = (tid < 272);

  float Af[17], Ag[17];
  if (act) {
    const float2* pc = (const float2*)(pred + b * NKP * 2);
    const float2* tc = (const float2*)(targ + b * NKP * 2);
    const float2 xi = pc[r];  // pred point for f-row r
    const float2 yj = tc[r];  // target point for g-row r
#pragma unroll
    for (int k = 0; k < 17; ++k) {
      const int j = q * 17 + k;
      float2 y = tc[j];
      float d0 = xi.x - y.x, d1 = xi.y - y.y;
      Af[k] = LOG_A - INV_EPS * (d0 * d0 + d1 * d1);
      float2 xx = pc[j];
      d0 = xx.x - yj.x; d1 = xx.y - yj.y;
      Ag[k] = LOG_A - INV_EPS * (d0 * d0 + d1 * d1);
    }
  }
  if (tid < NKP) { fsh[tid] = 0.0f; gsh[tid] = 0.0f; }
  __syncthreads();

  for (int it = 0; it < SK_ITERS; ++it) {
    // ---- f update: LSE over j (uses g) ----
    {
      float z[17];
      float m = -3.0e38f, s = 0.0f;
      if (act) {
#pragma unroll
        for (int k = 0; k < 17; ++k) {
          z[k] = fmaf(INV_EPS, gsh[q * 17 + k], Af[k]);
          m = fmaxf(m, z[k]);
        }
      }
      m = fmaxf(m, __shfl_xor(m, 1));
      m = fmaxf(m, __shfl_xor(m, 2));
      if (act) {
#pragma unroll
        for (int k = 0; k < 17; ++k) s += expf(z[k] - m);
      }
      s += __shfl_xor(s, 1);
      s += __shfl_xor(s, 2);
      if (act && q == 0) fsh[r] = NEG_EPS * (m + logf(s));
    }
    __syncthreads();
    // ---- g update: LSE over i (uses new f) ----
    {
      float z[17];
      float m = -3.0e38f, s = 0.0f;
      if (act) {
#pragma unroll
        for (int k = 0; k < 17; ++k) {
          z[k] = fmaf(INV_EPS, fsh[q * 17 + k], Ag[k]);
          m = fmaxf(m, z[k]);
        }
      }
      m = fmaxf(m, __shfl_xor(m, 1));
      m = fmaxf(m, __shfl_xor(m, 2));
      if (act) {
#pragma unroll
        for (int k = 0; k < 17; ++k) s += expf(z[k] - m);
      }
      s += __shfl_xor(s, 1);
      s += __shfl_xor(s, 2);
      if (act && q == 0) gsh[r] = NEG_EPS * (m + logf(s));
    }
    __syncthreads();
  }

  // ---- transport cost: sum exp((f_i+g_j-C)/eps + 2 log_a) * C ----
  float local = 0.0f;
  if (act) {
    const float base = fmaf(INV_EPS, fsh[r], LOG_A);
#pragma unroll
    for (int k = 0; k < 17; ++k) {
      float zz = base + fmaf(INV_EPS, gsh[q * 17 + k], Af[k]);
      float Cij = (LOG_A - Af[k]) * 0.01f;
      local += expf(zz) * Cij;
    }
  }
  for (int o = 32; o; o >>= 1) local += __shfl_down(local, o);
  const int w = tid >> 6;
  if ((tid & 63) == 0) wred[w] = local;
  __syncthreads();
  if (tid == 0) {
    float tot = 0;
    for (int i = 0; i < 5; i++) tot += wred[i];
    ws[WS_COST + b] = tot;
  }
}

// ---------------------------------------------------------------------------
// BCE: each block = one batch x 8-row y-tile. gy staged in LDS, gx recomputed.
// ---------------------------------------------------------------------------
__device__ void bce_part(const float* __restrict__ pred,
                         const float* __restrict__ targ,
                         float* __restrict__ ws, int bidx) {
  __shared__ __attribute__((aligned(16))) float gyp8[NKP][8];
  __shared__ __attribute__((aligned(16))) float gyt8[NKP][8];
  __shared__ float pxp_s[NKP], pxt_s[NKP];

  const int b = bidx >> 5;
  const int y0 = (bidx & 31) * 8;
  const int tid = threadIdx.x;

  for (int idx = tid; idx < NKP * 2; idx += 320) {
    const int n = idx >> 1, tsel = idx & 1;
    const float* c = tsel ? targ : pred;
    float v = c[(b * NKP + n) * 2] * 255.0f;
    (tsel ? pxt_s : pxp_s)[n] = v;
  }
  for (int idx = tid; idx < NKP * 16; idx += 320) {
    const int t2 = idx & 1, rr = (idx >> 1) & 7, n = idx >> 4;
    const float* c = t2 ? targ : pred;
    float py = c[(b * NKP + n) * 2 + 1] * 255.0f;
    float dy = (float)(y0 + rr) - py;
    float g = expf(-dy * dy * INVV);
    (t2 ? gyt8 : gyp8)[n][rr] = g;
  }
  __syncthreads();

  float accp[8] = {0, 0, 0, 0, 0, 0, 0, 0};
  float acct[8] = {0, 0, 0, 0, 0, 0, 0, 0};
  if (tid < 256) {
    const float fx = (float)tid;
    for (int n = 0; n < NKP; ++n) {
      float dxp = fx - pxp_s[n];
      float gxp = expf(-dxp * dxp * INVV);
      float dxt = fx - pxt_s[n];
      float gxt = expf(-dxt * dxt * INVV);
      const float4 gp0 = *(const float4*)&gyp8[n][0];
      const float4 gp1 = *(const float4*)&gyp8[n][4];
      const float4 gt0 = *(const float4*)&gyt8[n][0];
      const float4 gt1 = *(const float4*)&gyt8[n][4];
      accp[0] = fmaf(gp0.x, gxp, accp[0]);
      accp[1] = fmaf(gp0.y, gxp, accp[1]);
      accp[2] = fmaf(gp0.z, gxp, accp[2]);
      accp[3] = fmaf(gp0.w, gxp, accp[3]);
      accp[4] = fmaf(gp1.x, gxp, accp[4]);
      accp[5] = fmaf(gp1.y, gxp, accp[5]);
      accp[6] = fmaf(gp1.z, gxp, accp[6]);
      accp[7] = fmaf(gp1.w, gxp, accp[7]);
      acct[0] = fmaf(gt0.x, gxt, acct[0]);
      acct[1] = fmaf(gt0.y, gxt, acct[1]);
      acct[2] = fmaf(gt0.z, gxt, acct[2]);
      acct[3] = fmaf(gt0.w, gxt, acct[3]);
      acct[4] = fmaf(gt1.x, gxt, acct[4]);
      acct[5] = fmaf(gt1.y, gxt, acct[5]);
      acct[6] = fmaf(gt1.z, gxt, acct[6]);
      acct[7] = fmaf(gt1.w, gxt, acct[7]);
    }
  }

  float local = 0.0f;
  if (tid < 256) {
    const float rsp = 1.0f / (ws[WS_SP + b] + 1e-8f);
    const float rst = 1.0f / ws[WS_ST + b];
#pragma unroll
    for (int rr = 0; rr < 8; ++rr) {
      float p = accp[rr] * rsp;
      float t = acct[rr] * rst;
      float lp = fmaxf(logf(p), -100.0f);
      float l1 = fmaxf(log1pf(-p), -100.0f);
      local += t * lp + (1.0f - t) * l1;
    }
  }
  for (int o = 32; o; o >>= 1) local += __shfl_down(local, o);
  if ((tid & 63) == 0) atomicAdd(&ws[WS_BCE], local);
}

// ---------------------------------------------------------------------------
// Fused main kernel: blocks 0..15 sinkhorn, 16..527 BCE
// ---------------------------------------------------------------------------
__global__ __launch_bounds__(320) void k_main(const float* __restrict__ pred,
                                              const float* __restrict__ targ,
                                              float* __restrict__ ws) {
  if (blockIdx.x < 16)
    sink_part(pred, targ, ws, blockIdx.x);
  else
    bce_part(pred, targ, ws, blockIdx.x - 16);
}

// ---------------------------------------------------------------------------
// Final combine
// ---------------------------------------------------------------------------
__global__ void k_final(const float* __restrict__ ws, float* __restrict__ out) {
  if (threadIdx.x == 0) {
    float cs = 0;
    for (int b = 0; b < NB; b++) cs += ws[WS_COST + b];
    float was = cs * (1.0f / 16.0f) * 2000.0f;
    float bce = -ws[WS_BCE] * (1.0f / 1048576.0f) * 1000000.0f;
    out[0] = bce + was;
  }
}

extern "C" void kernel_launch(void* const* d_in, const int* in_sizes, int n_in,
                              void* d_out, int out_size, void* d_ws, size_t ws_size,
                              hipStream_t stream) {
  const float* pred = (const float*)d_in[0];
  const float* targ = (const float*)d_in[1];
  float* ws = (float*)d_ws;
  float* out = (float*)d_out;

  hipMemsetAsync(d_ws, 0, 64 * sizeof(float), stream);
  k_sums<<<dim3(NKP, NB), 256, 0, stream>>>(pred, targ, ws);
  k_main<<<16 + NB * 32, 320, 0, stream>>>(pred, targ, ws);
  k_final<<<1, 64, 0, stream>>>(ws, out);
}

// Round 2
// 53.852 us; speedup vs baseline: 2.7119x; 2.7119x over previous
//
#include <hip/hip_runtime.h>
#include <math.h>

#define NKP 68
#define NB 16
#define SK_ITERS 50

#define INVV 0.03125f                  // 1/(2*sigma^2), sigma=4
#define LOG_A (-4.219507705176107f)    // -log(68)
#define L2E 1.4426950408889634f
#define LN2 0.6931471805599453f
#define KGF (100.0f * L2E)             // (1/eps)*log2(e)
#define NEG_EPS_LN2 (-0.01f * LN2)
#define SHIFT 64.0f
#define C2X (INVV * -1.4426950408889634f)  // gaussian exponent, base-2

// workspace float offsets
#define WS_SP   0    // [16] pred heatmap sums
#define WS_ST   16   // [16] target heatmap sums
#define WS_BCE  32   // [1]  bce accumulation (zeroed by k_sums)
#define WS_COST 33   // [16] sinkhorn per-batch cost

__device__ __forceinline__ float E2(float x) {
#if __has_builtin(__builtin_amdgcn_exp2f)
  return __builtin_amdgcn_exp2f(x);
#else
  return exp2f(x);
#endif
}
__device__ __forceinline__ float L2(float x) {
#if __has_builtin(__builtin_amdgcn_logf)
  return __builtin_amdgcn_logf(x);   // v_log_f32 = log2
#else
  return log2f(x);
#endif
}
__device__ __forceinline__ float dpp_xor1_add(float s) {
#if __has_builtin(__builtin_amdgcn_mov_dpp)
  int t = __builtin_amdgcn_mov_dpp(__float_as_int(s), 0xB1, 0xF, 0xF, true);
  return s + __int_as_float(t);
#else
  return s + __shfl_xor(s, 1);
#endif
}

// ---------------------------------------------------------------------------
// k_sums: one block per batch. 272 tasks = (n, slot) where slot selects one of
// {pred-x, pred-y, targ-x, targ-y}; each task sums 256 gaussian samples.
// S_b = sum_n (sum_y gy)(sum_x gx). Plain stores, no atomics, no memset needed.
// ---------------------------------------------------------------------------
__global__ __launch_bounds__(320) void k_sums(const float* __restrict__ pred,
                                              const float* __restrict__ targ,
                                              float* __restrict__ ws) {
  const int b = blockIdx.x, tid = threadIdx.x;
  __shared__ float ls[4][NKP];
  if (tid < 272) {
    const int n = tid >> 2, slot = tid & 3;
    const float* src = (slot < 2) ? pred : targ;
    const float c = src[(b * NKP + n) * 2 + (slot & 1)] * 255.0f;
    float s0 = 0, s1 = 0, s2 = 0, s3 = 0;
    float f0 = 0.0f - c, f1 = 1.0f - c, f2 = 2.0f - c, f3 = 3.0f - c;
#pragma unroll 4
    for (int v = 0; v < 64; ++v) {
      s0 += E2(f0 * f0 * C2X);
      s1 += E2(f1 * f1 * C2X);
      s2 += E2(f2 * f2 * C2X);
      s3 += E2(f3 * f3 * C2X);
      f0 += 4.0f; f1 += 4.0f; f2 += 4.0f; f3 += 4.0f;
    }
    ls[slot][n] = (s0 + s1) + (s2 + s3);
  }
  __syncthreads();
  if (tid < 64) {
    float sp = ls[0][tid] * ls[1][tid];
    float st = ls[2][tid] * ls[3][tid];
    if (tid < 4) {
      sp += ls[0][64 + tid] * ls[1][64 + tid];
      st += ls[2][64 + tid] * ls[3][64 + tid];
    }
    for (int o = 32; o; o >>= 1) { sp += __shfl_down(sp, o); st += __shfl_down(st, o); }
    if (tid == 0) {
      ws[WS_SP + b] = sp;
      ws[WS_ST + b] = st;
      if (b == 0) ws[WS_BCE] = 0.0f;
    }
  }
}

// ---------------------------------------------------------------------------
// Sinkhorn: 2 lanes per row, 136 active lanes (3 waves). Base-2 LSE with a
// fixed +64 exponent shift (no per-update max). Padded LDS layout [2*36].
// ---------------------------------------------------------------------------
__device__ void sink_part(const float* __restrict__ pred,
                          const float* __restrict__ targ,
                          float* __restrict__ ws, int b) {
  __shared__ float fsh[72], gsh[72], wred[5];
  const int tid = threadIdx.x;
  const bool act = tid < 136;
  const int r = tid >> 1, q = tid & 1;
  const int q36 = q * 36;

  float A2f[34], A2g[34];
  int wofs = 0;
  if (act) {
    const float2* pc = (const float2*)(pred + b * NKP * 2);
    const float2* tc = (const float2*)(targ + b * NKP * 2);
    const float2 xi = pc[r];   // pred point, f-row r
    const float2 yj = tc[r];   // targ point, g-row r
#pragma unroll
    for (int k = 0; k < 34; ++k) {
      const int j = q * 34 + k;
      float2 y = tc[j];
      float d0 = xi.x - y.x, d1 = xi.y - y.y;
      A2f[k] = fmaf(-100.0f * L2E, d0 * d0 + d1 * d1, LOG_A * L2E + SHIFT);
      float2 x2 = pc[j];
      d0 = x2.x - yj.x; d1 = x2.y - yj.y;
      A2g[k] = fmaf(-100.0f * L2E, d0 * d0 + d1 * d1, LOG_A * L2E + SHIFT);
    }
    wofs = (r >= 34) ? (36 + r - 34) : r;
  }
  if (tid < 72) { fsh[tid] = 0.0f; gsh[tid] = 0.0f; }
  __syncthreads();

#define SINK_HALF(SRC, DST, A2)                                              \
  {                                                                          \
    float sa0 = 0, sa1 = 0, sa2 = 0, sa3 = 0;                                \
    if (act) {                                                               \
      float gl[36];                                                          \
      const float4* gv = (const float4*)&SRC[q36];                           \
      *(float4*)&gl[0]  = gv[0];                                             \
      *(float4*)&gl[4]  = gv[1];                                             \
      *(float4*)&gl[8]  = gv[2];                                             \
      *(float4*)&gl[12] = gv[3];                                             \
      *(float4*)&gl[16] = gv[4];                                             \
      *(float4*)&gl[20] = gv[5];                                             \
      *(float4*)&gl[24] = gv[6];                                             \
      *(float4*)&gl[28] = gv[7];                                             \
      *(float2*)&gl[32] = *(const float2*)&SRC[q36 + 32];                    \
      _Pragma("unroll")                                                      \
      for (int k = 0; k < 34; ++k) {                                         \
        float e = E2(fmaf(KGF, gl[k], A2[k]));                               \
        if ((k & 3) == 0) sa0 += e;                                          \
        else if ((k & 3) == 1) sa1 += e;                                     \
        else if ((k & 3) == 2) sa2 += e;                                     \
        else sa3 += e;                                                       \
      }                                                                      \
    }                                                                        \
    float s = (sa0 + sa1) + (sa2 + sa3);                                     \
    s = dpp_xor1_add(s);                                                     \
    if (act && q == 0) DST[wofs] = NEG_EPS_LN2 * (L2(s) - SHIFT);            \
  }

#pragma unroll 1
  for (int it = 0; it < SK_ITERS; ++it) {
    SINK_HALF(gsh, fsh, A2f)   // f update (reads g)
    __syncthreads();
    SINK_HALF(fsh, gsh, A2g)   // g update (reads new f)
    __syncthreads();
  }

  // transport cost: sum exp2(log2 P) * C
  float local = 0.0f;
  if (act) {
    const float fr = fsh[wofs];
    const float base = fmaf(KGF, fr, L2E * LOG_A - SHIFT);
    float gl[36];
    const float4* gv = (const float4*)&gsh[q36];
    *(float4*)&gl[0]  = gv[0];
    *(float4*)&gl[4]  = gv[1];
    *(float4*)&gl[8]  = gv[2];
    *(float4*)&gl[12] = gv[3];
    *(float4*)&gl[16] = gv[4];
    *(float4*)&gl[20] = gv[5];
    *(float4*)&gl[24] = gv[6];
    *(float4*)&gl[28] = gv[7];
    *(float2*)&gl[32] = *(const float2*)&gsh[q36 + 32];
#pragma unroll
    for (int k = 0; k < 34; ++k) {
      float lp2 = base + fmaf(KGF, gl[k], A2f[k]);
      float Cij = fmaf(-LN2, A2f[k] - SHIFT, LOG_A) * 0.01f;
      local += E2(lp2) * Cij;
    }
  }
  for (int o = 32; o; o >>= 1) local += __shfl_down(local, o);
  const int w = tid >> 6;
  if ((tid & 63) == 0) wred[w] = local;
  __syncthreads();
  if (tid == 0) {
    float tot = 0;
    for (int i = 0; i < 5; i++) tot += wred[i];
    ws[WS_COST + b] = tot;
  }
}

// ---------------------------------------------------------------------------
// BCE: block = one batch x 8-row y-tile. gy staged in LDS, gx recomputed.
// ---------------------------------------------------------------------------
__device__ void bce_part(const float* __restrict__ pred,
                         const float* __restrict__ targ,
                         float* __restrict__ ws, int bidx) {
  __shared__ __attribute__((aligned(16))) float gyp8[NKP][8];
  __shared__ __attribute__((aligned(16))) float gyt8[NKP][8];
  __shared__ float pxp_s[NKP], pxt_s[NKP];

  const int b = bidx >> 5;
  const int y0 = (bidx & 31) * 8;
  const int tid = threadIdx.x;

  for (int idx = tid; idx < NKP * 2; idx += 320) {
    const int n = idx >> 1, tsel = idx & 1;
    const float* c = tsel ? targ : pred;
    float v = c[(b * NKP + n) * 2] * 255.0f;
    (tsel ? pxt_s : pxp_s)[n] = v;
  }
  for (int idx = tid; idx < NKP * 16; idx += 320) {
    const int t2 = idx & 1, rr = (idx >> 1) & 7, n = idx >> 4;
    const float* c = t2 ? targ : pred;
    float py = c[(b * NKP + n) * 2 + 1] * 255.0f;
    float dy = (float)(y0 + rr) - py;
    (t2 ? gyt8 : gyp8)[n][rr] = E2(dy * dy * C2X);
  }
  __syncthreads();

  float accp[8] = {0, 0, 0, 0, 0, 0, 0, 0};
  float acct[8] = {0, 0, 0, 0, 0, 0, 0, 0};
  if (tid < 256) {
    const float fx = (float)tid;
    for (int n = 0; n < NKP; ++n) {
      float dxp = fx - pxp_s[n];
      float gxp = E2(dxp * dxp * C2X);
      float dxt = fx - pxt_s[n];
      float gxt = E2(dxt * dxt * C2X);
      const float4 gp0 = *(const float4*)&gyp8[n][0];
      const float4 gp1 = *(const float4*)&gyp8[n][4];
      const float4 gt0 = *(const float4*)&gyt8[n][0];
      const float4 gt1 = *(const float4*)&gyt8[n][4];
      accp[0] = fmaf(gp0.x, gxp, accp[0]);
      accp[1] = fmaf(gp0.y, gxp, accp[1]);
      accp[2] = fmaf(gp0.z, gxp, accp[2]);
      accp[3] = fmaf(gp0.w, gxp, accp[3]);
      accp[4] = fmaf(gp1.x, gxp, accp[4]);
      accp[5] = fmaf(gp1.y, gxp, accp[5]);
      accp[6] = fmaf(gp1.z, gxp, accp[6]);
      accp[7] = fmaf(gp1.w, gxp, accp[7]);
      acct[0] = fmaf(gt0.x, gxt, acct[0]);
      acct[1] = fmaf(gt0.y, gxt, acct[1]);
      acct[2] = fmaf(gt0.z, gxt, acct[2]);
      acct[3] = fmaf(gt0.w, gxt, acct[3]);
      acct[4] = fmaf(gt1.x, gxt, acct[4]);
      acct[5] = fmaf(gt1.y, gxt, acct[5]);
      acct[6] = fmaf(gt1.z, gxt, acct[6]);
      acct[7] = fmaf(gt1.w, gxt, acct[7]);
    }
  }

  float local = 0.0f;
  if (tid < 256) {
    const float rsp = 1.0f / (ws[WS_SP + b] + 1e-8f);
    const float rst = 1.0f / ws[WS_ST + b];
#pragma unroll
    for (int rr = 0; rr < 8; ++rr) {
      float p = accp[rr] * rsp;
      float t = acct[rr] * rst;
      float lp = fmaxf(logf(p), -100.0f);
      float l1 = fmaxf(log1pf(-p), -100.0f);
      local += t * lp + (1.0f - t) * l1;
    }
  }
  for (int o = 32; o; o >>= 1) local += __shfl_down(local, o);
  if ((tid & 63) == 0) atomicAdd(&ws[WS_BCE], local);
}

// ---------------------------------------------------------------------------
// Fused main kernel: blocks 0..15 sinkhorn, 16..527 BCE
// ---------------------------------------------------------------------------
__global__ __launch_bounds__(320) void k_main(const float* __restrict__ pred,
                                              const float* __restrict__ targ,
                                              float* __restrict__ ws) {
  if (blockIdx.x < 16)
    sink_part(pred, targ, ws, blockIdx.x);
  else
    bce_part(pred, targ, ws, blockIdx.x - 16);
}

// ---------------------------------------------------------------------------
// Final combine
// ---------------------------------------------------------------------------
__global__ void k_final(const float* __restrict__ ws, float* __restrict__ out) {
  if (threadIdx.x == 0) {
    float cs = 0;
    for (int b = 0; b < NB; b++) cs += ws[WS_COST + b];
    float was = cs * (1.0f / 16.0f) * 2000.0f;
    float bce = -ws[WS_BCE] * (1.0f / 1048576.0f) * 1000000.0f;
    out[0] = bce + was;
  }
}

extern "C" void kernel_launch(void* const* d_in, const int* in_sizes, int n_in,
                              void* d_out, int out_size, void* d_ws, size_t ws_size,
                              hipStream_t stream) {
  const float* pred = (const float*)d_in[0];
  const float* targ = (const float*)d_in[1];
  float* ws = (float*)d_ws;
  float* out = (float*)d_out;

  k_sums<<<NB, 320, 0, stream>>>(pred, targ, ws);
  k_main<<<16 + NB * 32, 320, 0, stream>>>(pred, targ, ws);
  k_final<<<1, 64, 0, stream>>>(ws, out);
}

// Round 3
// 45.449 us; speedup vs baseline: 3.2133x; 1.1849x over previous
//
#include <hip/hip_runtime.h>
#include <math.h>

#define NKP 68
#define NB 16
#define SK_ITERS 50

#define INVV 0.03125f                  // 1/(2*sigma^2), sigma=4
#define LOG_A (-4.219507705176107f)    // -log(68)
#define L2E 1.4426950408889634f
#define LN2 0.6931471805599453f
#define KGF (100.0f * L2E)             // (1/eps)*log2(e)
#define NEG_EPS_LN2 (-0.01f * LN2)
#define SHIFT 64.0f
#define FBIAS (0.01f * 0.6931471805599453f * 64.0f)   // -NEG_EPS_LN2*SHIFT
#define C2X (-INVV * 1.4426950408889634f)  // gaussian exponent, base-2

// workspace float offsets (all plain stores, no init needed)
#define WS_COST 0    // [16]  sinkhorn per-batch cost
#define WS_BCE0 16   // [512] per-block bce partial sums

__device__ __forceinline__ float E2(float x) {
#if __has_builtin(__builtin_amdgcn_exp2f)
  return __builtin_amdgcn_exp2f(x);
#else
  return exp2f(x);
#endif
}
__device__ __forceinline__ float L2(float x) {
#if __has_builtin(__builtin_amdgcn_logf)
  return __builtin_amdgcn_logf(x);   // v_log_f32 = log2
#else
  return log2f(x);
#endif
}
// sum over a quad of lanes (DPP quad_perm xor1 then xor2) — all 4 lanes get total
__device__ __forceinline__ float quad_sum(float s) {
#if __has_builtin(__builtin_amdgcn_mov_dpp)
  int a = __builtin_amdgcn_mov_dpp(__float_as_int(s), 0xB1, 0xF, 0xF, true);
  s += __int_as_float(a);
  int b2 = __builtin_amdgcn_mov_dpp(__float_as_int(s), 0x4E, 0xF, 0xF, true);
  s += __int_as_float(b2);
  return s;
#else
  s += __shfl_xor(s, 1);
  s += __shfl_xor(s, 2);
  return s;
#endif
}

// ---------------------------------------------------------------------------
// Sinkhorn: 4 lanes per row, 272 active lanes. Base-2 LSE with fixed +64
// exponent shift (no per-update max). LDS groups padded to 20 floats so each
// lane's 17-column slice is 16B-aligned; quad bases hit disjoint banks.
// ---------------------------------------------------------------------------
__device__ void sink_part(const float* __restrict__ pred,
                          const float* __restrict__ targ,
                          float* __restrict__ ws, int b) {
  __shared__ float fsh[80], gsh[80], wred[5];
  const int tid = threadIdx.x;
  const bool act = tid < 272;
  const int r = tid >> 2, q = tid & 3;
  const int rb = q * 20;               // read base (16B aligned)

  float A2f[17], A2g[17];
  int wofs = 0;
  if (act) {
    const float2* pc = (const float2*)(pred + b * NKP * 2);
    const float2* tc = (const float2*)(targ + b * NKP * 2);
    const float2 xi = pc[r];   // pred point, f-row r
    const float2 yj = tc[r];   // targ point, g-row r
#pragma unroll
    for (int k = 0; k < 17; ++k) {
      const int j = q * 17 + k;
      float2 y = tc[j];
      float d0 = xi.x - y.x, d1 = xi.y - y.y;
      A2f[k] = fmaf(-KGF, d0 * d0 + d1 * d1, LOG_A * L2E + SHIFT);
      float2 x2 = pc[j];
      d0 = x2.x - yj.x; d1 = x2.y - yj.y;
      A2g[k] = fmaf(-KGF, d0 * d0 + d1 * d1, LOG_A * L2E + SHIFT);
    }
    // padded write offset: (r/17)*20 + r%17
    wofs = (r >= 51) ? r + 9 : (r >= 34) ? r + 6 : (r >= 17) ? r + 3 : r;
  }
  if (tid < 80) { fsh[tid] = 0.0f; gsh[tid] = 0.0f; }
  __syncthreads();

#define SINK_HALF(SRC, DST, A2)                                              \
  {                                                                          \
    float s0 = 0, s1 = 0, s2 = 0, s3 = 0;                                    \
    if (act) {                                                               \
      float gl[17];                                                          \
      const float4* gv = (const float4*)&SRC[rb];                            \
      *(float4*)&gl[0]  = gv[0];                                             \
      *(float4*)&gl[4]  = gv[1];                                             \
      *(float4*)&gl[8]  = gv[2];                                             \
      *(float4*)&gl[12] = gv[3];                                             \
      gl[16] = SRC[rb + 16];                                                 \
      _Pragma("unroll")                                                      \
      for (int k = 0; k < 17; ++k) {                                         \
        float e = E2(fmaf(KGF, gl[k], A2[k]));                               \
        if ((k & 3) == 0) s0 += e;                                           \
        else if ((k & 3) == 1) s1 += e;                                      \
        else if ((k & 3) == 2) s2 += e;                                      \
        else s3 += e;                                                        \
      }                                                                      \
    }                                                                        \
    float s = (s0 + s1) + (s2 + s3);                                         \
    s = quad_sum(s);                                                         \
    if (act && q == 0) DST[wofs] = fmaf(NEG_EPS_LN2, L2(s), FBIAS);          \
  }

#pragma unroll 1
  for (int it = 0; it < SK_ITERS; ++it) {
    SINK_HALF(gsh, fsh, A2f)   // f update (reads g)
    __syncthreads();
    SINK_HALF(fsh, gsh, A2g)   // g update (reads new f)
    __syncthreads();
  }

  // transport cost: sum exp2(log2 P) * C
  float local = 0.0f;
  if (act) {
    const float fr = fsh[wofs];
    const float base = fmaf(KGF, fr, L2E * LOG_A - SHIFT);
    float gl[17];
    const float4* gv = (const float4*)&gsh[rb];
    *(float4*)&gl[0]  = gv[0];
    *(float4*)&gl[4]  = gv[1];
    *(float4*)&gl[8]  = gv[2];
    *(float4*)&gl[12] = gv[3];
    gl[16] = gsh[rb + 16];
#pragma unroll
    for (int k = 0; k < 17; ++k) {
      float lp2 = base + fmaf(KGF, gl[k], A2f[k]);
      float Cij = fmaf(-LN2, A2f[k] - SHIFT, LOG_A) * 0.01f;
      local += E2(lp2) * Cij;
    }
  }
  for (int o = 32; o; o >>= 1) local += __shfl_down(local, o);
  if ((tid & 63) == 0) wred[tid >> 6] = local;
  __syncthreads();
  if (tid == 0) {
    float tot = 0;
    for (int i = 0; i < 5; i++) tot += wred[i];
    ws[WS_COST + b] = tot;
  }
}

// ---------------------------------------------------------------------------
// BCE: block = one batch x 8-row y-tile. Per-block redundant computation of
// the batch normalization sums (hidden under sinkhorn critical path), then
// gy staged in LDS, gx recomputed, per-block partial to its own ws slot.
// ---------------------------------------------------------------------------
__device__ void bce_part(const float* __restrict__ pred,
                         const float* __restrict__ targ,
                         float* __restrict__ ws, int bidx) {
  __shared__ float ls[4][NKP];
  __shared__ __attribute__((aligned(16))) float gyp8[NKP][8];
  __shared__ __attribute__((aligned(16))) float gyt8[NKP][8];
  __shared__ float pxp_s[NKP], pxt_s[NKP];
  __shared__ float sS[2];
  __shared__ float bred[5];

  const int b = bidx >> 5;
  const int y0 = (bidx & 31) * 8;
  const int tid = threadIdx.x;

  // phase 1a: per-(n,axis) 256-sample gaussian sums (for normalization)
  if (tid < 272) {
    const int n = tid >> 2, slot = tid & 3;          // slot: 0 px,1 py,2 tx,3 ty
    const float* src = (slot < 2) ? pred : targ;
    const float c = src[(b * NKP + n) * 2 + (slot & 1)] * 255.0f;
    float s0 = 0, s1 = 0, s2 = 0, s3 = 0;
    float f0 = 0.0f - c, f1 = 1.0f - c, f2 = 2.0f - c, f3 = 3.0f - c;
#pragma unroll 4
    for (int v = 0; v < 64; ++v) {
      s0 += E2(f0 * f0 * C2X);
      s1 += E2(f1 * f1 * C2X);
      s2 += E2(f2 * f2 * C2X);
      s3 += E2(f3 * f3 * C2X);
      f0 += 4.0f; f1 += 4.0f; f2 += 4.0f; f3 += 4.0f;
    }
    ls[slot][n] = (s0 + s1) + (s2 + s3);
  }
  // phase 1b: stage px and gy tiles
  for (int idx = tid; idx < NKP * 2; idx += 320) {
    const int n = idx >> 1, tsel = idx & 1;
    const float* c = tsel ? targ : pred;
    float v = c[(b * NKP + n) * 2] * 255.0f;
    (tsel ? pxt_s : pxp_s)[n] = v;
  }
  for (int idx = tid; idx < NKP * 16; idx += 320) {
    const int t2 = idx & 1, rr = (idx >> 1) & 7, n = idx >> 4;
    const float* c = t2 ? targ : pred;
    float py = c[(b * NKP + n) * 2 + 1] * 255.0f;
    float dy = (float)(y0 + rr) - py;
    (t2 ? gyt8 : gyp8)[n][rr] = E2(dy * dy * C2X);
  }
  __syncthreads();

  // reduce ls -> S_p, S_t
  if (tid < 64) {
    float sp = ls[0][tid] * ls[1][tid];
    float st = ls[2][tid] * ls[3][tid];
    if (tid < 4) {
      sp += ls[0][64 + tid] * ls[1][64 + tid];
      st += ls[2][64 + tid] * ls[3][64 + tid];
    }
    for (int o = 32; o; o >>= 1) { sp += __shfl_down(sp, o); st += __shfl_down(st, o); }
    if (tid == 0) { sS[0] = sp; sS[1] = st; }
  }
  __syncthreads();

  // phase 2: heatmap accumulation over keypoints
  float accp[8] = {0, 0, 0, 0, 0, 0, 0, 0};
  float acct[8] = {0, 0, 0, 0, 0, 0, 0, 0};
  if (tid < 256) {
    const float fx = (float)tid;
    for (int n = 0; n < NKP; ++n) {
      float dxp = fx - pxp_s[n];
      float gxp = E2(dxp * dxp * C2X);
      float dxt = fx - pxt_s[n];
      float gxt = E2(dxt * dxt * C2X);
      const float4 gp0 = *(const float4*)&gyp8[n][0];
      const float4 gp1 = *(const float4*)&gyp8[n][4];
      const float4 gt0 = *(const float4*)&gyt8[n][0];
      const float4 gt1 = *(const float4*)&gyt8[n][4];
      accp[0] = fmaf(gp0.x, gxp, accp[0]);
      accp[1] = fmaf(gp0.y, gxp, accp[1]);
      accp[2] = fmaf(gp0.z, gxp, accp[2]);
      accp[3] = fmaf(gp0.w, gxp, accp[3]);
      accp[4] = fmaf(gp1.x, gxp, accp[4]);
      accp[5] = fmaf(gp1.y, gxp, accp[5]);
      accp[6] = fmaf(gp1.z, gxp, accp[6]);
      accp[7] = fmaf(gp1.w, gxp, accp[7]);
      acct[0] = fmaf(gt0.x, gxt, acct[0]);
      acct[1] = fmaf(gt0.y, gxt, acct[1]);
      acct[2] = fmaf(gt0.z, gxt, acct[2]);
      acct[3] = fmaf(gt0.w, gxt, acct[3]);
      acct[4] = fmaf(gt1.x, gxt, acct[4]);
      acct[5] = fmaf(gt1.y, gxt, acct[5]);
      acct[6] = fmaf(gt1.z, gxt, acct[6]);
      acct[7] = fmaf(gt1.w, gxt, acct[7]);
    }
  }

  // phase 3: bce terms
  float local = 0.0f;
  if (tid < 256) {
    const float rsp = 1.0f / (sS[0] + 1e-8f);
    const float rst = 1.0f / sS[1];
#pragma unroll
    for (int rr = 0; rr < 8; ++rr) {
      float p = accp[rr] * rsp;
      float t = acct[rr] * rst;
      float lp = fmaxf(logf(p), -100.0f);
      float l1 = fmaxf(log1pf(-p), -100.0f);
      local += t * lp + (1.0f - t) * l1;
    }
  }
  for (int o = 32; o; o >>= 1) local += __shfl_down(local, o);
  if ((tid & 63) == 0) bred[tid >> 6] = local;
  __syncthreads();
  if (tid == 0) {
    float t = bred[0] + bred[1] + bred[2] + bred[3] + bred[4];
    ws[WS_BCE0 + bidx] = t;   // plain store, no atomics
  }
}

// ---------------------------------------------------------------------------
// Fused main kernel: blocks 0..15 sinkhorn, 16..527 BCE
// ---------------------------------------------------------------------------
__global__ __launch_bounds__(320) void k_main(const float* __restrict__ pred,
                                              const float* __restrict__ targ,
                                              float* __restrict__ ws) {
  if (blockIdx.x < 16)
    sink_part(pred, targ, ws, blockIdx.x);
  else
    bce_part(pred, targ, ws, blockIdx.x - 16);
}

// ---------------------------------------------------------------------------
// Final combine: reduce 512 bce partials + 16 costs
// ---------------------------------------------------------------------------
__global__ __launch_bounds__(256) void k_final(const float* __restrict__ ws,
                                               float* __restrict__ out) {
  const int tid = threadIdx.x;
  __shared__ float redb[4], redc[4];
  float vb = ws[WS_BCE0 + tid] + ws[WS_BCE0 + 256 + tid];
  float vc = (tid < NB) ? ws[WS_COST + tid] : 0.0f;
  for (int o = 32; o; o >>= 1) { vb += __shfl_down(vb, o); vc += __shfl_down(vc, o); }
  if ((tid & 63) == 0) { redb[tid >> 6] = vb; redc[tid >> 6] = vc; }
  __syncthreads();
  if (tid == 0) {
    float B = redb[0] + redb[1] + redb[2] + redb[3];
    float C = redc[0] + redc[1] + redc[2] + redc[3];
    out[0] = -B * (1000000.0f / 1048576.0f) + C * (2000.0f / 16.0f);
  }
}

extern "C" void kernel_launch(void* const* d_in, const int* in_sizes, int n_in,
                              void* d_out, int out_size, void* d_ws, size_t ws_size,
                              hipStream_t stream) {
  const float* pred = (const float*)d_in[0];
  const float* targ = (const float*)d_in[1];
  float* ws = (float*)d_ws;
  float* out = (float*)d_out;

  k_main<<<16 + NB * 32, 320, 0, stream>>>(pred, targ, ws);
  k_final<<<1, 256, 0, stream>>>(ws, out);
}

// Round 4
// 35.154 us; speedup vs baseline: 4.1543x; 1.2928x over previous
//
#include <hip/hip_runtime.h>
#include <math.h>

#define NKP 68
#define NB 16
#define SK_ITERS 50

#define INVV 0.03125f                  // 1/(2*sigma^2), sigma=4
#define LOG_A (-4.219507705176107f)    // -log(68)
#define L2E 1.4426950408889634f
#define KGF (100.0f * L2E)             // (1/eps)*log2(e)
#define SW 40.0f                       // power-of-two shift baked into W
#define C2X (-INVV * 1.4426950408889634f)  // gaussian exponent, base-2

// workspace float offsets (all plain stores, no init needed)
#define WS_COST 0     // [16]   sinkhorn per-batch cost
#define WS_BCE0 16    // [1024] per-block bce partial sums

__device__ __forceinline__ float E2(float x) {
#if __has_builtin(__builtin_amdgcn_exp2f)
  return __builtin_amdgcn_exp2f(x);
#else
  return exp2f(x);
#endif
}
__device__ __forceinline__ float RCP(float x) {
#if __has_builtin(__builtin_amdgcn_rcpf)
  return __builtin_amdgcn_rcpf(x);   // v_rcp_f32, ~1 ulp
#else
  return 1.0f / x;
#endif
}
// sum over lane pair (DPP quad_perm xor1) — both lanes get the total
__device__ __forceinline__ float dpp_xor1_add(float s) {
#if __has_builtin(__builtin_amdgcn_mov_dpp)
  int t = __builtin_amdgcn_mov_dpp(__float_as_int(s), 0xB1, 0xF, 0xF, true);
  return s + __int_as_float(t);
#else
  return s + __shfl_xor(s, 1);
#endif
}

// ---------------------------------------------------------------------------
// Sinkhorn in SCALING form: u = 2^40 / (W v), v = 2^40 / (W^T u), where
// W_ij = 2^40 e^{-C_ij/eps} / N is precomputed per lane. No transcendentals
// in the 100-step serial loop: 34 FMA + 1 DPP add + 1 v_rcp per half-update.
// 2 lanes per row, 136 active lanes in 3 waves.
// ---------------------------------------------------------------------------
__device__ void sink_part(const float* __restrict__ pred,
                          const float* __restrict__ targ,
                          float* __restrict__ ws, int b) {
  __shared__ float ush[80], vsh[80], wred[3];
  const int tid = threadIdx.x;
  const bool act = tid < 136;
  const int r = tid >> 1, q = tid & 1;
  const int rb = q * 40;               // LDS read base (16B aligned, padded groups of 40)

  float Wf[34], Wg[34], WC[34];
  int wofs = 0;
  if (act) {
    const float2* pc = (const float2*)(pred + b * NKP * 2);
    const float2* tc = (const float2*)(targ + b * NKP * 2);
    const float2 xi = pc[r];   // pred point, f-row r
    const float2 yj = tc[r];   // targ point, g-row r
#pragma unroll
    for (int k = 0; k < 34; ++k) {
      const int j = q * 34 + k;
      float2 y = tc[j];
      float d0 = xi.x - y.x, d1 = xi.y - y.y;
      float c = d0 * d0 + d1 * d1;
      Wf[k] = E2(fmaf(-KGF, c, L2E * LOG_A + SW));
      WC[k] = Wf[k] * c;
      float2 x2 = pc[j];
      d0 = x2.x - yj.x; d1 = x2.y - yj.y;
      float c2 = d0 * d0 + d1 * d1;
      Wg[k] = E2(fmaf(-KGF, c2, L2E * LOG_A + SW));
    }
    wofs = (r < 34) ? r : r + 6;       // padded write offset
  }
  if (tid < 80) vsh[tid] = 1.0f;       // v0 = exp(g0/eps) = 1
  __syncthreads();

#define LOAD34(DST, SRC)                                                     \
  {                                                                          \
    const float4* gv = (const float4*)&SRC[rb];                              \
    *(float4*)&DST[0]  = gv[0];                                              \
    *(float4*)&DST[4]  = gv[1];                                              \
    *(float4*)&DST[8]  = gv[2];                                              \
    *(float4*)&DST[12] = gv[3];                                              \
    *(float4*)&DST[16] = gv[4];                                              \
    *(float4*)&DST[20] = gv[5];                                              \
    *(float4*)&DST[24] = gv[6];                                              \
    *(float4*)&DST[28] = gv[7];                                              \
    *(float2*)&DST[32] = *(const float2*)&SRC[rb + 32];                      \
  }

#define SINK_HALF(SRC, DST, W, RESULT)                                       \
  {                                                                          \
    float s0 = 0, s1 = 0, s2 = 0, s3 = 0;                                    \
    if (act) {                                                               \
      float gl[34];                                                          \
      LOAD34(gl, SRC)                                                        \
      _Pragma("unroll")                                                      \
      for (int k = 0; k < 34; ++k) {                                         \
        float t = W[k] * gl[k];                                              \
        if ((k & 3) == 0) s0 += t;                                           \
        else if ((k & 3) == 1) s1 += t;                                      \
        else if ((k & 3) == 2) s2 += t;                                      \
        else s3 += t;                                                        \
      }                                                                      \
    }                                                                        \
    float s = (s0 + s1) + (s2 + s3);                                         \
    s = dpp_xor1_add(s);                                                     \
    RESULT = RCP(s) * 0x1p+40f;                                              \
    if (act && q == 0) DST[wofs] = RESULT;                                   \
  }

  float u = 0.0f, v = 0.0f;
#pragma unroll 1
  for (int it = 0; it < SK_ITERS; ++it) {
    SINK_HALF(vsh, ush, Wf, u)   // f-half: u = 2^40 / (W v)
    __syncthreads();
    SINK_HALF(ush, vsh, Wg, v)   // g-half: v = 2^40 / (W^T u)
    __syncthreads();
  }
  (void)v;

  // transport cost: cost_b = 2^-40/N * sum_i u_i * sum_j (W_ij C_ij) v_j
  float local = 0.0f;
  if (act) {
    float gl[34];
    LOAD34(gl, vsh)
    float c0 = 0, c1 = 0, c2 = 0, c3 = 0;
#pragma unroll
    for (int k = 0; k < 34; ++k) {
      float t = WC[k] * gl[k];
      if ((k & 3) == 0) c0 += t;
      else if ((k & 3) == 1) c1 += t;
      else if ((k & 3) == 2) c2 += t;
      else c3 += t;
    }
    float sc = (c0 + c1) + (c2 + c3);
    sc = dpp_xor1_add(sc);
    if (q == 0) local = sc * u;
  }
  for (int o = 32; o; o >>= 1) local += __shfl_down(local, o);
  if ((tid & 63) == 0) wred[tid >> 6] = local;
  __syncthreads();
  if (tid == 0)
    ws[WS_COST + b] = (wred[0] + wred[1] + wred[2]) * (0x1p-40f / 68.0f);
}

// ---------------------------------------------------------------------------
// BCE: block = one batch x 8-row y-tile x 128-col x-half. Windowed (40-sample)
// per-axis gaussian sums for normalization; gy staged in LDS; gx recomputed.
// ---------------------------------------------------------------------------
__device__ void bce_part(const float* __restrict__ pred,
                         const float* __restrict__ targ,
                         float* __restrict__ ws, int bidx) {
  __shared__ float ls[4][NKP];
  __shared__ __attribute__((aligned(16))) float gyp8[NKP][8];
  __shared__ __attribute__((aligned(16))) float gyt8[NKP][8];
  __shared__ float pxp_s[NKP], pxt_s[NKP];
  __shared__ float sS[2];
  __shared__ float bred[3];

  const int b = bidx >> 6;
  const int t6 = bidx & 63;
  const int y0 = (t6 >> 1) * 8;
  const int xbase = (t6 & 1) * 128;
  const int tid = threadIdx.x;

  // phase 1a: windowed per-(n,axis) gaussian sums (tail < 2e-5 absolute)
  for (int idx = tid; idx < 272; idx += 192) {
    const int n = idx >> 2, slot = idx & 3;          // 0 px,1 py,2 tx,3 ty
    const float* src = (slot < 2) ? pred : targ;
    const float c = src[(b * NKP + n) * 2 + (slot & 1)] * 255.0f;
    int x0 = (int)c - 19;
    x0 = max(0, min(216, x0));
    float g0 = (float)x0 - c, g1 = g0 + 1.0f, g2 = g0 + 2.0f, g3 = g0 + 3.0f;
    float s0 = 0, s1 = 0, s2 = 0, s3 = 0;
#pragma unroll 2
    for (int v = 0; v < 10; ++v) {
      s0 += E2(g0 * g0 * C2X);
      s1 += E2(g1 * g1 * C2X);
      s2 += E2(g2 * g2 * C2X);
      s3 += E2(g3 * g3 * C2X);
      g0 += 4.0f; g1 += 4.0f; g2 += 4.0f; g3 += 4.0f;
    }
    ls[slot][n] = (s0 + s1) + (s2 + s3);
  }
  // phase 1b: stage x-centers and gy tiles
  for (int idx = tid; idx < NKP * 2; idx += 192) {
    const int n = idx >> 1, tsel = idx & 1;
    const float* c = tsel ? targ : pred;
    float v = c[(b * NKP + n) * 2] * 255.0f;
    (tsel ? pxt_s : pxp_s)[n] = v;
  }
  for (int idx = tid; idx < NKP * 16; idx += 192) {
    const int t2 = idx & 1, rr = (idx >> 1) & 7, n = idx >> 4;
    const float* c = t2 ? targ : pred;
    float py = c[(b * NKP + n) * 2 + 1] * 255.0f;
    float dy = (float)(y0 + rr) - py;
    (t2 ? gyt8 : gyp8)[n][rr] = E2(dy * dy * C2X);
  }
  __syncthreads();

  // reduce ls -> S_p, S_t
  if (tid < 64) {
    float sp = ls[0][tid] * ls[1][tid];
    float st = ls[2][tid] * ls[3][tid];
    if (tid < 4) {
      sp += ls[0][64 + tid] * ls[1][64 + tid];
      st += ls[2][64 + tid] * ls[3][64 + tid];
    }
    for (int o = 32; o; o >>= 1) { sp += __shfl_down(sp, o); st += __shfl_down(st, o); }
    if (tid == 0) { sS[0] = sp; sS[1] = st; }
  }
  __syncthreads();

  // phase 2: heatmap accumulation over keypoints (128 x-threads)
  float accp[8] = {0, 0, 0, 0, 0, 0, 0, 0};
  float acct[8] = {0, 0, 0, 0, 0, 0, 0, 0};
  if (tid < 128) {
    const float fx = (float)(xbase + tid);
    for (int n = 0; n < NKP; ++n) {
      float dxp = fx - pxp_s[n];
      float gxp = E2(dxp * dxp * C2X);
      float dxt = fx - pxt_s[n];
      float gxt = E2(dxt * dxt * C2X);
      const float4 gp0 = *(const float4*)&gyp8[n][0];
      const float4 gp1 = *(const float4*)&gyp8[n][4];
      const float4 gt0 = *(const float4*)&gyt8[n][0];
      const float4 gt1 = *(const float4*)&gyt8[n][4];
      accp[0] = fmaf(gp0.x, gxp, accp[0]);
      accp[1] = fmaf(gp0.y, gxp, accp[1]);
      accp[2] = fmaf(gp0.z, gxp, accp[2]);
      accp[3] = fmaf(gp0.w, gxp, accp[3]);
      accp[4] = fmaf(gp1.x, gxp, accp[4]);
      accp[5] = fmaf(gp1.y, gxp, accp[5]);
      accp[6] = fmaf(gp1.z, gxp, accp[6]);
      accp[7] = fmaf(gp1.w, gxp, accp[7]);
      acct[0] = fmaf(gt0.x, gxt, acct[0]);
      acct[1] = fmaf(gt0.y, gxt, acct[1]);
      acct[2] = fmaf(gt0.z, gxt, acct[2]);
      acct[3] = fmaf(gt0.w, gxt, acct[3]);
      acct[4] = fmaf(gt1.x, gxt, acct[4]);
      acct[5] = fmaf(gt1.y, gxt, acct[5]);
      acct[6] = fmaf(gt1.z, gxt, acct[6]);
      acct[7] = fmaf(gt1.w, gxt, acct[7]);
    }
  }

  // phase 3: bce terms
  float local = 0.0f;
  if (tid < 128) {
    const float rsp = 1.0f / (sS[0] + 1e-8f);
    const float rst = 1.0f / sS[1];
#pragma unroll
    for (int rr = 0; rr < 8; ++rr) {
      float p = accp[rr] * rsp;
      float t = acct[rr] * rst;
      float lp = fmaxf(logf(p), -100.0f);
      float l1 = fmaxf(log1pf(-p), -100.0f);
      local += t * lp + (1.0f - t) * l1;
    }
  }
  for (int o = 32; o; o >>= 1) local += __shfl_down(local, o);
  if ((tid & 63) == 0) bred[tid >> 6] = local;
  __syncthreads();
  if (tid == 0)
    ws[WS_BCE0 + bidx] = bred[0] + bred[1] + bred[2];   // plain store
}

// ---------------------------------------------------------------------------
// Fused main kernel: blocks 0..15 sinkhorn, 16..1039 BCE
// ---------------------------------------------------------------------------
__global__ __launch_bounds__(192) void k_main(const float* __restrict__ pred,
                                              const float* __restrict__ targ,
                                              float* __restrict__ ws) {
  if (blockIdx.x < 16)
    sink_part(pred, targ, ws, blockIdx.x);
  else
    bce_part(pred, targ, ws, blockIdx.x - 16);
}

// ---------------------------------------------------------------------------
// Final combine: reduce 1024 bce partials + 16 costs
// ---------------------------------------------------------------------------
__global__ __launch_bounds__(256) void k_final(const float* __restrict__ ws,
                                               float* __restrict__ out) {
  const int tid = threadIdx.x;
  __shared__ float redb[4], redc[4];
  float vb = 0.0f;
#pragma unroll
  for (int i = 0; i < 4; ++i) vb += ws[WS_BCE0 + tid + 256 * i];
  float vc = (tid < NB) ? ws[WS_COST + tid] : 0.0f;
  for (int o = 32; o; o >>= 1) { vb += __shfl_down(vb, o); vc += __shfl_down(vc, o); }
  if ((tid & 63) == 0) { redb[tid >> 6] = vb; redc[tid >> 6] = vc; }
  __syncthreads();
  if (tid == 0) {
    float B = redb[0] + redb[1] + redb[2] + redb[3];
    float C = redc[0] + redc[1] + redc[2] + redc[3];
    out[0] = -B * (1000000.0f / 1048576.0f) + C * (2000.0f / 16.0f);
  }
}

extern "C" void kernel_launch(void* const* d_in, const int* in_sizes, int n_in,
                              void* d_out, int out_size, void* d_ws, size_t ws_size,
                              hipStream_t stream) {
  const float* pred = (const float*)d_in[0];
  const float* targ = (const float*)d_in[1];
  float* ws = (float*)d_ws;
  float* out = (float*)d_out;

  k_main<<<16 + NB * 64, 192, 0, stream>>>(pred, targ, ws);
  k_final<<<1, 256, 0, stream>>>(ws, out);
}